// Round 7
// baseline (16409.085 us; speedup 1.0000x reference)
//
#include <hip/hip_runtime.h>
#include <cstdint>

typedef unsigned long long u64;

#define B_   64
#define L_   1024
#define D_   256
#define H_   256
#define G4_  1024
#define NROW (B_*L_)   // 65536

#define MAGR 0x7E570001u
#define MAGB 0x7E570002u

// ===================== Kernel 1: xproj = x @ W_ih^T + b_ih (unchanged) =====================
#define TM 128
#define TN 128
#define KC 16

__global__ __launch_bounds__(256)
void xproj_gemm(const float* __restrict__ x, const float* __restrict__ Wih,
                const float* __restrict__ bih, float* __restrict__ xp)
{
  __shared__ float As[2][KC][TM];
  __shared__ float Bs[2][KC][TN];
  const int tid = threadIdx.x;
  const int bn = blockIdx.x & 7;
  const int bm = blockIdx.x >> 3;
  const long R0 = (long)bm * TM;
  const int  C0 = bn * TN;
  const int tx = tid & 15, ty = tid >> 4;

  float acc[8][8];
#pragma unroll
  for (int i = 0; i < 8; i++)
#pragma unroll
    for (int j = 0; j < 8; j++) acc[i][j] = 0.f;

  float4 areg[2], breg[2];

#pragma unroll
  for (int rep = 0; rep < 2; rep++) {
    int f4 = rep * 256 + tid;
    int rw = f4 & 127, kq = f4 >> 7;
    areg[rep] = *(const float4*)(x   + (R0 + rw) * D_ + kq * 4);
    breg[rep] = *(const float4*)(Wih + (long)(C0 + rw) * D_ + kq * 4);
  }
#pragma unroll
  for (int rep = 0; rep < 2; rep++) {
    int f4 = rep * 256 + tid;
    int rw = f4 & 127, kq = f4 >> 7;
#pragma unroll
    for (int i2 = 0; i2 < 4; i2++) {
      As[0][kq * 4 + i2][rw] = ((const float*)&areg[rep])[i2];
      Bs[0][kq * 4 + i2][rw] = ((const float*)&breg[rep])[i2];
    }
  }
  __syncthreads();

  int buf = 0;
  const int NKB = D_ / KC;
  for (int kb = 0; kb < NKB; kb++) {
    if (kb + 1 < NKB) {
#pragma unroll
      for (int rep = 0; rep < 2; rep++) {
        int f4 = rep * 256 + tid;
        int rw = f4 & 127, kq = f4 >> 7;
        areg[rep] = *(const float4*)(x   + (R0 + rw) * D_ + (kb + 1) * KC + kq * 4);
        breg[rep] = *(const float4*)(Wih + (long)(C0 + rw) * D_ + (kb + 1) * KC + kq * 4);
      }
    }
#pragma unroll
    for (int kk = 0; kk < KC; kk++) {
      float4 a0 = *(const float4*)&As[buf][kk][tx * 4];
      float4 a1 = *(const float4*)&As[buf][kk][tx * 4 + 64];
      float4 b0 = *(const float4*)&Bs[buf][kk][ty * 4];
      float4 b1 = *(const float4*)&Bs[buf][kk][ty * 4 + 64];
      float av[8] = {a0.x,a0.y,a0.z,a0.w,a1.x,a1.y,a1.z,a1.w};
      float bv[8] = {b0.x,b0.y,b0.z,b0.w,b1.x,b1.y,b1.z,b1.w};
#pragma unroll
      for (int i = 0; i < 8; i++)
#pragma unroll
        for (int j = 0; j < 8; j++) acc[i][j] += av[i] * bv[j];
    }
    if (kb + 1 < NKB) {
#pragma unroll
      for (int rep = 0; rep < 2; rep++) {
        int f4 = rep * 256 + tid;
        int rw = f4 & 127, kq = f4 >> 7;
#pragma unroll
        for (int i2 = 0; i2 < 4; i2++) {
          As[buf ^ 1][kq * 4 + i2][rw] = ((const float*)&areg[rep])[i2];
          Bs[buf ^ 1][kq * 4 + i2][rw] = ((const float*)&breg[rep])[i2];
        }
      }
    }
    __syncthreads();
    buf ^= 1;
  }

  float4 bb0 = *(const float4*)(bih + C0 + ty * 4);
  float4 bb1 = *(const float4*)(bih + C0 + ty * 4 + 64);
#pragma unroll
  for (int i = 0; i < 8; i++) {
    long m = R0 + tx * 4 + ((i < 4) ? i : (60 + i));
    float4 v0, v1;
    v0.x = acc[i][0] + bb0.x; v0.y = acc[i][1] + bb0.y;
    v0.z = acc[i][2] + bb0.z; v0.w = acc[i][3] + bb0.w;
    v1.x = acc[i][4] + bb1.x; v1.y = acc[i][5] + bb1.y;
    v1.z = acc[i][6] + bb1.z; v1.w = acc[i][7] + bb1.w;
    *(float4*)(xp + m * G4_ + C0 + ty * 4)      = v0;
    *(float4*)(xp + m * G4_ + C0 + ty * 4 + 64) = v1;
  }
}

// ===================== Kernel 2: persistent recurrence =====================
// 16 chains x 16 blocks. Stores are ALWAYS agent-scope (L3-visible, R1-proven).
// Readers adaptively use sc0 (XCD-L2) loads while they keep succeeding; on a
// 2000-spin budget miss they switch STICKY to agent-scope loads. Correct for
// any XCD placement / any sc0 cache semantics; fast when L2 path is live.

__device__ __forceinline__ void load8(const u64* p, u64 o[8], int sc0mode)
{
  if (sc0mode) {
    asm volatile(
      "global_load_dwordx2 %0, %8, off sc0\n\t"
      "global_load_dwordx2 %1, %8, off offset:8 sc0\n\t"
      "global_load_dwordx2 %2, %8, off offset:16 sc0\n\t"
      "global_load_dwordx2 %3, %8, off offset:24 sc0\n\t"
      "global_load_dwordx2 %4, %8, off offset:32 sc0\n\t"
      "global_load_dwordx2 %5, %8, off offset:40 sc0\n\t"
      "global_load_dwordx2 %6, %8, off offset:48 sc0\n\t"
      "global_load_dwordx2 %7, %8, off offset:56 sc0\n\t"
      "s_waitcnt vmcnt(0)"
      : "=&v"(o[0]), "=&v"(o[1]), "=&v"(o[2]), "=&v"(o[3]),
        "=&v"(o[4]), "=&v"(o[5]), "=&v"(o[6]), "=&v"(o[7])
      : "v"(p)
      : "memory");
  } else {
#pragma unroll
    for (int i = 0; i < 8; i++)
      o[i] = __hip_atomic_load(p + i, __ATOMIC_RELAXED, __HIP_MEMORY_SCOPE_AGENT);
  }
}

__global__ __launch_bounds__(512, 2)
void lstm_recur(const float* __restrict__ xp, const float* __restrict__ mask,
                const float* __restrict__ Whh, const float* __restrict__ bhh,
                float* __restrict__ out, u64* __restrict__ hstate,
                u64* __restrict__ regw, u64* __restrict__ bmapw)
{
  __shared__ __align__(16) float hbuf[4][260];     // h_{t-1}; rows padded; doubles as leader scratch
  __shared__ float4 part[8][4][16];                // [kc][r][cc] -> (i,f,g,o) partials
  __shared__ float mbuf[2][4];
  __shared__ int shmap[3];

  static_assert(sizeof(hbuf) >= 3 * 256 * sizeof(int), "leader scratch must fit in hbuf");

  const int tid = threadIdx.x;
  const int bid = blockIdx.x;

  // ---------- phase 0: self-organization (agent-scope only) ----------
  if (tid == 0) {
    int xcc = __builtin_amdgcn_s_getreg((3 << 11) | (0 << 6) | 20) & 15;  // HW_REG_XCC_ID[3:0]
    __hip_atomic_store(regw + bid, ((u64)MAGR << 32) | (u64)xcc,
                       __ATOMIC_RELAXED, __HIP_MEMORY_SCOPE_AGENT);

    if (bid == 0) {
      int* lab = (int*)&hbuf[0][0];      // 256 ints
      int* slt = lab + 256;              // 256 ints
      int* gch = slt + 256;              // 256 ints
      for (int b = 0; b < 256; b++) lab[b] = -1;
      int remaining = 256, iter = 0;
      while (remaining > 0 && iter < 60000) {
        for (int b = 0; b < 256; b += 8) {
          int any = 0;
          for (int i = 0; i < 8; i++) any |= (lab[b + i] < 0);
          if (!any) continue;
          u64 v[8];
#pragma unroll
          for (int i = 0; i < 8; i++)
            v[i] = __hip_atomic_load(regw + b + i, __ATOMIC_RELAXED, __HIP_MEMORY_SCOPE_AGENT);
          for (int i = 0; i < 8; i++)
            if (lab[b + i] < 0 && (unsigned)(v[i] >> 32) == MAGR) {
              lab[b + i] = (int)(v[i] & 15); remaining--;
            }
        }
        iter++;
      }
      if (remaining > 0) {
        for (int b = 0; b < 256; b++) {
          u64 mm = ((u64)MAGB << 32) | (u64)((b >> 4) | ((b & 15) << 8) | (1u << 16));
          __hip_atomic_store(bmapw + b, mm, __ATOMIC_RELAXED, __HIP_MEMORY_SCOPE_AGENT);
        }
      } else {
        int cntb[16];
        for (int l = 0; l < 16; l++) cntb[l] = 0;
        for (int b = 0; b < 256; b++) slt[b] = cntb[lab[b]]++;
        int cnext = 0;
        for (int l = 0; l < 16; l++) {
          int ng = cntb[l] >> 4;
          for (int g = 0; g < 16; g++)
            gch[l * 16 + g] = (g < ng && cnext < 16) ? cnext++ : -1;
        }
        int pool0 = cnext, pi = 0;
        for (int b = 0; b < 256; b++) {
          int l = lab[b], s = slt[b], g = s >> 4, m = s & 15;
          int chain, mem, tier;
          if (g < 16 && gch[l * 16 + g] >= 0) { chain = gch[l * 16 + g]; mem = m; tier = 0; }
          else { int idx = pi++; chain = pool0 + (idx >> 4); mem = idx & 15; tier = 1; }
          u64 mm = ((u64)MAGB << 32) | (u64)(chain | (mem << 8) | (tier << 16));
          __hip_atomic_store(bmapw + b, mm, __ATOMIC_RELAXED, __HIP_MEMORY_SCOPE_AGENT);
        }
      }
    }
    int chain = bid >> 4, mem = bid & 15, tier = 1;
    for (int it = 0; it < 200000; it++) {
      u64 v = __hip_atomic_load(bmapw + bid, __ATOMIC_RELAXED, __HIP_MEMORY_SCOPE_AGENT);
      if ((unsigned)(v >> 32) == MAGB) {
        unsigned p = (unsigned)v;
        chain = p & 255; mem = (p >> 8) & 255; tier = (p >> 16) & 255;
        break;
      }
    }
    shmap[0] = chain; shmap[1] = mem; shmap[2] = tier;
  }
  __syncthreads();

  const int chain = shmap[0];
  const int gg    = shmap[1];     // gate col group 0..15
  const int tier  = shmap[2];     // 0 = try XCD-L2 reads first, 1 = agent reads

  // ---------- thread roles ----------
  const int kc = tid >> 6;          // 0..7 : k-chunk of 32
  const int r  = (tid >> 4) & 3;    // batch row in chain
  const int cc = tid & 15;          // col within gate group

  // W_hh fragment: 4 gate types x 32 k  (128 VGPRs)
  float4 wreg[4][8];
#pragma unroll
  for (int q = 0; q < 4; q++) {
    const float* wr = Whh + (long)(q * H_ + gg * 16 + cc) * H_ + kc * 32;
#pragma unroll
    for (int u = 0; u < 8; u++) wreg[q][u] = *(const float4*)(wr + u * 4);
  }

  // elementwise role (tid<64): (er, ec)
  const int er = tid >> 4, ec = tid & 15;
  const long erow = (long)chain * 4 + er;
  float bq[4], xq[4];
  if (tid < 64) {
#pragma unroll
    for (int q = 0; q < 4; q++) bq[q] = bhh[q * H_ + gg * 16 + ec];
#pragma unroll
    for (int q = 0; q < 4; q++)
      xq[q] = xp[(erow * L_ + 0) * G4_ + q * H_ + gg * 16 + ec];
  }
  if (tid < 4) mbuf[1][tid] = mask[((long)chain * 4 + tid) * L_];

  // poll role (tid<128): row, word segment
  const int prow = tid >> 5, pseg = tid & 31;

  float hreg = 0.f, creg = 0.f;
  int dead = 0;
  int sc0mode = (tier == 0);   // sticky: drops to agent loads after one budget miss
  __syncthreads();

  for (int s = 1; s <= 2048; s++) {
    const int t   = (s <= 1024) ? (s - 1) : (2048 - s);
    const int sp  = (s < 2048) ? (s + 1) : 2048;
    const int tp  = (sp <= 1024) ? (sp - 1) : (2048 - sp);
    const int dir = (s <= 1024) ? 0 : 1;

    // prefetch next step's xp / mask (latency hidden under poll+compute)
    float xn[4];
    if (tid < 64) {
#pragma unroll
      for (int q = 0; q < 4; q++)
        xn[q] = xp[(erow * L_ + tp) * G4_ + q * H_ + gg * 16 + ec];
    }
    float mv = 0.f;
    if (tid < 4) mv = mask[((long)chain * 4 + tid) * L_ + tp];

    // acquire h_{s-1}: sc0 (L2) while it works, sticky-fallback to agent (L3)
    if (tid < 128) {
      if (s > 1) {
        const u64* hp = hstate + (size_t)((s - 1) & 1) * B_ * H_
                        + ((size_t)chain * 4 + prow) * H_ + pseg * 8;
        u64 uu[8];
        const unsigned want = (unsigned)(s - 1);
        int iter = 0, ok = 0;
        const int cap = dead ? 1 : 200000;
        do {
          load8(hp, uu, sc0mode);
          ok = 1;
#pragma unroll
          for (int i = 0; i < 8; i++) ok &= ((unsigned)(uu[i] >> 32) == want);
          if (!ok) {
            ++iter;
            if (sc0mode && iter >= 2000) { sc0mode = 0; iter = 0; }  // sticky switch
          }
        } while (!ok && iter < cap);
        if (!ok) dead = 1;
#pragma unroll
        for (int i = 0; i < 8; i++)
          hbuf[prow][pseg * 8 + i] = __uint_as_float((unsigned)uu[i]);
      } else {
#pragma unroll
        for (int i = 0; i < 8; i++) hbuf[prow][pseg * 8 + i] = 0.f;
      }
    }
    __syncthreads();   // bar1: hbuf ready

    // partial dots: 4 gate types x 32 k for (r, cc)
    float a0 = 0.f, a1 = 0.f, a2 = 0.f, a3 = 0.f;
#pragma unroll
    for (int u = 0; u < 8; u++) {
      float4 hv = *(const float4*)&hbuf[r][kc * 32 + u * 4];
      float4 w0 = wreg[0][u], w1 = wreg[1][u], w2 = wreg[2][u], w3 = wreg[3][u];
      a0 = fmaf(w0.x, hv.x, a0); a0 = fmaf(w0.y, hv.y, a0);
      a0 = fmaf(w0.z, hv.z, a0); a0 = fmaf(w0.w, hv.w, a0);
      a1 = fmaf(w1.x, hv.x, a1); a1 = fmaf(w1.y, hv.y, a1);
      a1 = fmaf(w1.z, hv.z, a1); a1 = fmaf(w1.w, hv.w, a1);
      a2 = fmaf(w2.x, hv.x, a2); a2 = fmaf(w2.y, hv.y, a2);
      a2 = fmaf(w2.z, hv.z, a2); a2 = fmaf(w2.w, hv.w, a2);
      a3 = fmaf(w3.x, hv.x, a3); a3 = fmaf(w3.y, hv.y, a3);
      a3 = fmaf(w3.z, hv.z, a3); a3 = fmaf(w3.w, hv.w, a3);
    }
    part[kc][r][cc] = make_float4(a0, a1, a2, a3);
    __syncthreads();   // bar2: partials ready

    // elementwise LSTM cell (tid<64)
    if (tid < 64) {
      float4 g4 = part[0][er][ec];
#pragma unroll
      for (int k2 = 1; k2 < 8; k2++) {
        float4 p4 = part[k2][er][ec];
        g4.x += p4.x; g4.y += p4.y; g4.z += p4.z; g4.w += p4.w;
      }
      float iv = g4.x + xq[0] + bq[0];
      float fv = g4.y + xq[1] + bq[1];
      float gv = g4.z + xq[2] + bq[2];
      float ov = g4.w + xq[3] + bq[3];
      float si = 1.f / (1.f + expf(-iv));
      float sf = 1.f / (1.f + expf(-fv));
      float so = 1.f / (1.f + expf(-ov));
      float c1 = sf * creg + si * tanhf(gv);
      float h1 = so * tanhf(c1);
      float m  = mbuf[s & 1][er];
      float hn = m * h1 + (1.f - m) * hreg;
      float cn = m * c1 + 1.f - m * creg;   // replicates reference parenthesization
      hreg = hn; creg = cn;

      out[erow * L_ * 512 + (long)t * 512 + dir * H_ + gg * 16 + ec] = hn;

      // store ALWAYS agent-scope: visible at L3 to any reader tier
      u64 pack = ((u64)(unsigned)s << 32) | (u64)__float_as_uint(hn);
      __hip_atomic_store(hstate + (size_t)(s & 1) * B_ * H_ + erow * H_ + gg * 16 + ec,
                         pack, __ATOMIC_RELAXED, __HIP_MEMORY_SCOPE_AGENT);

      if (s == 1024 || s == 2048) {
        const long off_hn = (long)B_ * L_ * 512;
        out[off_hn + erow * 512 + dir * H_ + gg * 16 + ec] = hn;
        out[off_hn + 32768 + erow * 512 + dir * H_ + gg * 16 + ec] = cn;
      }
#pragma unroll
      for (int q = 0; q < 4; q++) xq[q] = xn[q];
    }
    if (tid < 4) mbuf[(s + 1) & 1][tid] = mv;
  }
}

// ===================== launcher =====================
extern "C" void kernel_launch(void* const* d_in, const int* in_sizes, int n_in,
                              void* d_out, int out_size, void* d_ws, size_t ws_size,
                              hipStream_t stream)
{
  const float* x    = (const float*)d_in[0];
  const float* mask = (const float*)d_in[1];
  const float* Wih  = (const float*)d_in[2];
  const float* Whh  = (const float*)d_in[3];
  const float* bih  = (const float*)d_in[4];
  const float* bhh  = (const float*)d_in[5];
  float* out = (float*)d_out;

  float* xp     = (float*)d_ws;                                   // 256 MB
  u64*   hstate = (u64*)((char*)d_ws + (size_t)NROW * G4_ * 4);   // 256 KB
  u64*   regw   = hstate + (size_t)2 * B_ * H_;                   // 2 KB
  u64*   bmapw  = regw + 256;                                     // 2 KB

  const size_t need = (size_t)NROW * G4_ * 4 + (size_t)2 * B_ * H_ * 8 + 512 * 8;
  if (ws_size < need) return;

  xproj_gemm<<<dim3(512 * 8), dim3(256), 0, stream>>>(x, Wih, bih, xp);

  void* args[] = { (void*)&xp, (void*)&mask, (void*)&Whh, (void*)&bhh,
                   (void*)&out, (void*)&hstate, (void*)&regw, (void*)&bmapw };
  hipLaunchCooperativeKernel((void*)lstm_recur, dim3(256), dim3(512), args, 0, stream);
}

// Round 9
// 5980.827 us; speedup vs baseline: 2.7436x; 2.7436x over previous
//
#include <hip/hip_runtime.h>
#include <cstdint>

typedef unsigned long long u64;

#define B_   64
#define L_   1024
#define D_   256
#define H_   256
#define G4_  1024
#define NROW (B_*L_)   // 65536

// ===================== Kernel 1: xproj = x @ W_ih^T + b_ih (unchanged) =====================
#define TM 128
#define TN 128
#define KC 16

__global__ __launch_bounds__(256)
void xproj_gemm(const float* __restrict__ x, const float* __restrict__ Wih,
                const float* __restrict__ bih, float* __restrict__ xp)
{
  __shared__ float As[2][KC][TM];
  __shared__ float Bs[2][KC][TN];
  const int tid = threadIdx.x;
  const int bn = blockIdx.x & 7;
  const int bm = blockIdx.x >> 3;
  const long R0 = (long)bm * TM;
  const int  C0 = bn * TN;
  const int tx = tid & 15, ty = tid >> 4;

  float acc[8][8];
#pragma unroll
  for (int i = 0; i < 8; i++)
#pragma unroll
    for (int j = 0; j < 8; j++) acc[i][j] = 0.f;

  float4 areg[2], breg[2];

#pragma unroll
  for (int rep = 0; rep < 2; rep++) {
    int f4 = rep * 256 + tid;
    int rw = f4 & 127, kq = f4 >> 7;
    areg[rep] = *(const float4*)(x   + (R0 + rw) * D_ + kq * 4);
    breg[rep] = *(const float4*)(Wih + (long)(C0 + rw) * D_ + kq * 4);
  }
#pragma unroll
  for (int rep = 0; rep < 2; rep++) {
    int f4 = rep * 256 + tid;
    int rw = f4 & 127, kq = f4 >> 7;
#pragma unroll
    for (int i2 = 0; i2 < 4; i2++) {
      As[0][kq * 4 + i2][rw] = ((const float*)&areg[rep])[i2];
      Bs[0][kq * 4 + i2][rw] = ((const float*)&breg[rep])[i2];
    }
  }
  __syncthreads();

  int buf = 0;
  const int NKB = D_ / KC;
  for (int kb = 0; kb < NKB; kb++) {
    if (kb + 1 < NKB) {
#pragma unroll
      for (int rep = 0; rep < 2; rep++) {
        int f4 = rep * 256 + tid;
        int rw = f4 & 127, kq = f4 >> 7;
        areg[rep] = *(const float4*)(x   + (R0 + rw) * D_ + (kb + 1) * KC + kq * 4);
        breg[rep] = *(const float4*)(Wih + (long)(C0 + rw) * D_ + (kb + 1) * KC + kq * 4);
      }
    }
#pragma unroll
    for (int kk = 0; kk < KC; kk++) {
      float4 a0 = *(const float4*)&As[buf][kk][tx * 4];
      float4 a1 = *(const float4*)&As[buf][kk][tx * 4 + 64];
      float4 b0 = *(const float4*)&Bs[buf][kk][ty * 4];
      float4 b1 = *(const float4*)&Bs[buf][kk][ty * 4 + 64];
      float av[8] = {a0.x,a0.y,a0.z,a0.w,a1.x,a1.y,a1.z,a1.w};
      float bv[8] = {b0.x,b0.y,b0.z,b0.w,b1.x,b1.y,b1.z,b1.w};
#pragma unroll
      for (int i = 0; i < 8; i++)
#pragma unroll
        for (int j = 0; j < 8; j++) acc[i][j] += av[i] * bv[j];
    }
    if (kb + 1 < NKB) {
#pragma unroll
      for (int rep = 0; rep < 2; rep++) {
        int f4 = rep * 256 + tid;
        int rw = f4 & 127, kq = f4 >> 7;
#pragma unroll
        for (int i2 = 0; i2 < 4; i2++) {
          As[buf ^ 1][kq * 4 + i2][rw] = ((const float*)&areg[rep])[i2];
          Bs[buf ^ 1][kq * 4 + i2][rw] = ((const float*)&breg[rep])[i2];
        }
      }
    }
    __syncthreads();
    buf ^= 1;
  }

  float4 bb0 = *(const float4*)(bih + C0 + ty * 4);
  float4 bb1 = *(const float4*)(bih + C0 + ty * 4 + 64);
#pragma unroll
  for (int i = 0; i < 8; i++) {
    long m = R0 + tx * 4 + ((i < 4) ? i : (60 + i));
    float4 v0, v1;
    v0.x = acc[i][0] + bb0.x; v0.y = acc[i][1] + bb0.y;
    v0.z = acc[i][2] + bb0.z; v0.w = acc[i][3] + bb0.w;
    v1.x = acc[i][4] + bb1.x; v1.y = acc[i][5] + bb1.y;
    v1.z = acc[i][6] + bb1.z; v1.w = acc[i][7] + bb1.w;
    *(float4*)(xp + m * G4_ + C0 + ty * 4)      = v0;
    *(float4*)(xp + m * G4_ + C0 + ty * 4 + 64) = v1;
  }
}

// ===================== Kernel 2: persistent recurrence, pure agent-scope exchange ==========
// 16 chains (4 batch rows) x 16 blocks (16 h-cols each). No self-organization, no tiers.
// Roles within a 512-thread block:
//   - all 512:     W_hh partial dots (W fragment in VGPRs)
//   - tid <  64:   elementwise cell + out/h store (producers)
//   - tid 64..319: pollers for next step's h (4 tagged words each) — run CONCURRENTLY
//                  with the producers' phase, so detect latency overlaps store latency.
// h exchanged as tagged 8B words (tag=step) via relaxed agent atomics, parity double-buffer.

__global__ __launch_bounds__(512, 2)
void lstm_recur(const float* __restrict__ xp, const float* __restrict__ mask,
                const float* __restrict__ Whh, const float* __restrict__ bhh,
                float* __restrict__ out, u64* __restrict__ hstate)
{
  __shared__ __align__(16) float hbuf[4][260];     // h_{s-1}, rows padded for bank spread
  __shared__ float4 part[8][4][16];                // [kc][r][cc] -> (i,f,g,o) partials

  const int tid = threadIdx.x;
  const int bid = blockIdx.x;
  const int chain = bid >> 4;       // 0..15
  const int gg    = bid & 15;       // gate col group 0..15

  // ---------- FMA role (all threads) ----------
  const int kc = tid >> 6;          // 0..7 : k-chunk of 32
  const int r  = (tid >> 4) & 3;    // batch row in chain
  const int cc = tid & 15;          // col within gate group

  // W_hh fragment: 4 gate types x 32 k (128 VGPRs)
  float4 wreg[4][8];
#pragma unroll
  for (int q = 0; q < 4; q++) {
    const float* wr = Whh + (long)(q * H_ + gg * 16 + cc) * H_ + kc * 32;
#pragma unroll
    for (int u = 0; u < 8; u++) wreg[q][u] = *(const float4*)(wr + u * 4);
  }

  // ---------- elementwise role (tid<64) ----------
  const int er = tid >> 4, ec = tid & 15;
  const long erow = (long)chain * 4 + er;
  float bq[4], xq[4], mreg = 0.f;
  if (tid < 64) {
#pragma unroll
    for (int q = 0; q < 4; q++) bq[q] = bhh[q * H_ + gg * 16 + ec];
#pragma unroll
    for (int q = 0; q < 4; q++)
      xq[q] = xp[(erow * L_) * G4_ + q * H_ + gg * 16 + ec];
    mreg = mask[erow * L_];
  }

  // ---------- poll role (tid 64..319): 4 tagged words each ----------
  const int pidx = tid - 64;
  const int prow = pidx >> 6;       // 0..3
  const int pseg = pidx & 63;       // word group (4 u64 = 32B)

  // init hbuf = h_0 = 0
  if (tid >= 64 && tid < 320) {
#pragma unroll
    for (int i = 0; i < 4; i++) hbuf[prow][pseg * 4 + i] = 0.f;
  }

  float hreg = 0.f, creg = 0.f;
  int dead = 0;
  __syncthreads();   // hbuf(h_0) ready

  for (int s = 1; s <= 2048; s++) {
    const int t   = (s <= 1024) ? (s - 1) : (2048 - s);
    const int dir = (s <= 1024) ? 0 : 1;

    // ---- phase 1 (all): partial dots, 4 gate types x 32 k for (r, cc) ----
    float a0 = 0.f, a1 = 0.f, a2 = 0.f, a3 = 0.f;
#pragma unroll
    for (int u = 0; u < 8; u++) {
      float4 hv = *(const float4*)&hbuf[r][kc * 32 + u * 4];
      float4 w0 = wreg[0][u], w1 = wreg[1][u], w2 = wreg[2][u], w3 = wreg[3][u];
      a0 = fmaf(w0.x, hv.x, a0); a0 = fmaf(w0.y, hv.y, a0);
      a0 = fmaf(w0.z, hv.z, a0); a0 = fmaf(w0.w, hv.w, a0);
      a1 = fmaf(w1.x, hv.x, a1); a1 = fmaf(w1.y, hv.y, a1);
      a1 = fmaf(w1.z, hv.z, a1); a1 = fmaf(w1.w, hv.w, a1);
      a2 = fmaf(w2.x, hv.x, a2); a2 = fmaf(w2.y, hv.y, a2);
      a2 = fmaf(w2.z, hv.z, a2); a2 = fmaf(w2.w, hv.w, a2);
      a3 = fmaf(w3.x, hv.x, a3); a3 = fmaf(w3.y, hv.y, a3);
      a3 = fmaf(w3.z, hv.z, a3); a3 = fmaf(w3.w, hv.w, a3);
    }
    part[kc][r][cc] = make_float4(a0, a1, a2, a3);
    __syncthreads();   // partials ready; hbuf now free for rewrite

    // ---- phase 2: producers (tid<64) and pollers (64..319) run CONCURRENTLY ----
    if (tid < 64) {
      float4 g4 = part[0][er][ec];
#pragma unroll
      for (int k2 = 1; k2 < 8; k2++) {
        float4 p4 = part[k2][er][ec];
        g4.x += p4.x; g4.y += p4.y; g4.z += p4.z; g4.w += p4.w;
      }
      float iv = g4.x + xq[0] + bq[0];
      float fv = g4.y + xq[1] + bq[1];
      float gv = g4.z + xq[2] + bq[2];
      float ov = g4.w + xq[3] + bq[3];
      float si = 1.f / (1.f + expf(-iv));
      float sf = 1.f / (1.f + expf(-fv));
      float so = 1.f / (1.f + expf(-ov));
      float c1 = sf * creg + si * tanhf(gv);
      float h1 = so * tanhf(c1);
      float m  = mreg;
      float hn = m * h1 + (1.f - m) * hreg;
      float cn = m * c1 + 1.f - m * creg;   // replicates reference parenthesization
      hreg = hn; creg = cn;

      // publish h(s) FIRST (it's on the chain's critical path), then local out
      u64 pack = ((u64)(unsigned)s << 32) | (u64)__float_as_uint(hn);
      __hip_atomic_store(hstate + (size_t)(s & 1) * B_ * H_ + erow * H_ + gg * 16 + ec,
                         pack, __ATOMIC_RELAXED, __HIP_MEMORY_SCOPE_AGENT);

      out[erow * L_ * 512 + (long)t * 512 + dir * H_ + gg * 16 + ec] = hn;

      if (s == 1024 || s == 2048) {
        const long off_hn = (long)B_ * L_ * 512;
        out[off_hn + erow * 512 + dir * H_ + gg * 16 + ec] = hn;
        out[off_hn + 32768 + erow * 512 + dir * H_ + gg * 16 + ec] = cn;
      }

      // prefetch xp/mask for step s+1 (hidden under next FMA + poll)
      if (s < 2048) {
        const int sp = s + 1;
        const int tp = (sp <= 1024) ? (sp - 1) : (2048 - sp);
#pragma unroll
        for (int q = 0; q < 4; q++)
          xq[q] = xp[(erow * L_ + tp) * G4_ + q * H_ + gg * 16 + ec];
        mreg = mask[erow * L_ + tp];
      }
    } else if (tid < 320 && s < 2048) {
      // acquire h(s) for next step (tags == s), parity s&1
      const u64* hp = hstate + (size_t)(s & 1) * B_ * H_
                      + ((size_t)chain * 4 + prow) * H_ + pseg * 4;
      u64 uu[4];
      const unsigned want = (unsigned)s;
      int iter = 0, ok = 0;
      const int cap = dead ? 1 : 200000;
      do {
#pragma unroll
        for (int i = 0; i < 4; i++)
          uu[i] = __hip_atomic_load(hp + i, __ATOMIC_RELAXED, __HIP_MEMORY_SCOPE_AGENT);
        ok = 1;
#pragma unroll
        for (int i = 0; i < 4; i++) ok &= ((unsigned)(uu[i] >> 32) == want);
      } while (!ok && ++iter < cap);
      if (!ok) dead = 1;
#pragma unroll
      for (int i = 0; i < 4; i++)
        hbuf[prow][pseg * 4 + i] = __uint_as_float((unsigned)uu[i]);
    }
    __syncthreads();   // hbuf(h_s) ready for next iteration
  }
}

// ===================== launcher =====================
extern "C" void kernel_launch(void* const* d_in, const int* in_sizes, int n_in,
                              void* d_out, int out_size, void* d_ws, size_t ws_size,
                              hipStream_t stream)
{
  const float* x    = (const float*)d_in[0];
  const float* mask = (const float*)d_in[1];
  const float* Wih  = (const float*)d_in[2];
  const float* Whh  = (const float*)d_in[3];
  const float* bih  = (const float*)d_in[4];
  const float* bhh  = (const float*)d_in[5];
  float* out = (float*)d_out;

  float* xp     = (float*)d_ws;                                   // 256 MB
  u64*   hstate = (u64*)((char*)d_ws + (size_t)NROW * G4_ * 4);   // 256 KB

  const size_t need = (size_t)NROW * G4_ * 4 + (size_t)2 * B_ * H_ * 8;
  if (ws_size < need) return;

  xproj_gemm<<<dim3(512 * 8), dim3(256), 0, stream>>>(x, Wih, bih, xp);

  void* args[] = { (void*)&xp, (void*)&mask, (void*)&Whh, (void*)&bhh,
                   (void*)&out, (void*)&hstate };
  hipLaunchCooperativeKernel((void*)lstm_recur, dim3(256), dim3(512), args, 0, stream);
}